// Round 1
// baseline (1507.675 us; speedup 1.0000x reference)
//
#include <hip/hip_runtime.h>

// ---------------- problem constants ----------------
#define NN   128
#define CC   256
#define MH   28
#define MW   28
#define HW   784        // 28*28
#define KCLS 80
#define PP   196
#define SHH  200
#define SWW  200
#define SPIX 40000      // 200*200
#define FCIN 416        // C + 2K

// ---------------- K1: sem = relu(semantic_feat . w_sem^T + b) ----------------
// out layout: sem[pixel][o] (pixel-major, 256 contiguous channels per pixel)
__global__ __launch_bounds__(256) void sem_gemm_k(
    const float* __restrict__ semf, const float* __restrict__ w,
    const float* __restrict__ b, float* __restrict__ sem) {
  __shared__ __align__(16) float A[32 * 64];   // [k][m]
  __shared__ __align__(16) float B[32 * 68];   // [k][o] padded
  const int m0 = blockIdx.x * 64, o0 = blockIdx.y * 64;
  const int t = threadIdx.x, tm = t & 15, to = t >> 4;
  float acc[4][4] = {};
  for (int kc = 0; kc < 256; kc += 32) {
#pragma unroll
    for (int it = 0; it < 8; ++it) {
      int flat = it * 256 + t;
      int k = flat >> 6, m = flat & 63;
      A[k * 64 + m] = semf[(kc + k) * SPIX + m0 + m];
    }
#pragma unroll
    for (int it = 0; it < 8; ++it) {
      int flat = it * 256 + t;
      int o = flat >> 5, k = flat & 31;
      B[k * 68 + o] = w[(o0 + o) * 256 + kc + k];
    }
    __syncthreads();
#pragma unroll
    for (int k = 0; k < 32; ++k) {
      const float4 a4 = *(const float4*)&A[k * 64 + tm * 4];
      const float4 b4 = *(const float4*)&B[k * 68 + to * 4];
      const float av[4] = {a4.x, a4.y, a4.z, a4.w};
      const float bv[4] = {b4.x, b4.y, b4.z, b4.w};
#pragma unroll
      for (int i = 0; i < 4; ++i)
#pragma unroll
        for (int j = 0; j < 4; ++j) acc[i][j] += av[i] * bv[j];
    }
    __syncthreads();
  }
#pragma unroll
  for (int i = 0; i < 4; ++i) {
    float4 r;
    r.x = fmaxf(acc[i][0] + b[o0 + to * 4 + 0], 0.f);
    r.y = fmaxf(acc[i][1] + b[o0 + to * 4 + 1], 0.f);
    r.z = fmaxf(acc[i][2] + b[o0 + to * 4 + 2], 0.f);
    r.w = fmaxf(acc[i][3] + b[o0 + to * 4 + 3], 0.f);
    *(float4*)&sem[(m0 + tm * 4 + i) * 256 + o0 + to * 4] = r;
  }
}

// ---------------- K2: class-selected inst/det maps (outputs 0 & 1) ----------
// fp64 accumulate so our top-k ranking matches the high-precision reference.
__global__ __launch_bounds__(256) void select_maps_k(
    const float* __restrict__ inst, const int* __restrict__ labels,
    const float* __restrict__ w_inst, const float* __restrict__ b_inst,
    const float* __restrict__ w_det, const float* __restrict__ b_det,
    float* __restrict__ out0, float* __restrict__ out1) {
  const int n = blockIdx.x;
  const int s = blockIdx.y * 196 + threadIdx.x;
  if (threadIdx.x >= 196) return;
  const int lab = labels[n];
  const float* fi = inst + (size_t)n * CC * HW + s;
  const float* wi = w_inst + lab * 256;
  const float* wd = w_det + lab * 256;
  double ai = 0.0, ad = 0.0;
  for (int c = 0; c < 256; ++c) {
    const float v = fi[c * HW];
    ai += (double)v * (double)wi[c];
    ad += (double)v * (double)wd[c];
  }
  out0[n * HW + s] = (float)(ai + (double)b_inst[lab]);
  out1[n * HW + s] = (float)(ad + (double)b_det[lab]);
}

// ---------------- K3: per-n top-196 of 784 via bitonic sort ------------------
__global__ __launch_bounds__(256) void topk_k(const float* __restrict__ det,
                                              int* __restrict__ pidx) {
  __shared__ unsigned long long keys[1024];
  const int n = blockIdx.x;
  for (int i = threadIdx.x; i < 1024; i += 256) {
    unsigned long long kk = 0ull;
    if (i < HW) {
      unsigned u = __float_as_uint(det[n * HW + i]);
      u = (u & 0x80000000u) ? ~u : (u | 0x80000000u);
      kk = ((unsigned long long)u << 32) | (unsigned)(1023 - i);  // lower idx wins ties
    }
    keys[i] = kk;
  }
  __syncthreads();
  for (int k = 2; k <= 1024; k <<= 1) {
    for (int j = k >> 1; j > 0; j >>= 1) {
      for (int i = threadIdx.x; i < 1024; i += 256) {
        const int l = i ^ j;
        if (l > i) {
          const bool up = ((i & k) == 0);
          unsigned long long a = keys[i], bb = keys[l];
          if ((a > bb) == up) { keys[i] = bb; keys[l] = a; }
        }
      }
      __syncthreads();
    }
  }
  for (int r = threadIdx.x; r < PP; r += 256)
    pidx[n * PP + r] = 1023 - (int)(keys[828 + r] & 1023ull);
}

// ---------------- K4a: c_inst/c_det at selected points -> X,Y tails ----------
__global__ __launch_bounds__(256) void point_kc_k(
    const float* __restrict__ inst, const int* __restrict__ pidx,
    const float* __restrict__ w_inst, const float* __restrict__ b_inst,
    const float* __restrict__ w_det, const float* __restrict__ b_det,
    float* __restrict__ X, float* __restrict__ Y) {
  __shared__ float F[256 * 49];  // [c][p]
  __shared__ int idx[49];
  const int n = blockIdx.x, pt = blockIdx.y;  // 4 tiles of 49 points
  const int t = threadIdx.x;
  if (t < 49) idx[t] = pidx[n * PP + pt * 49 + t];
  __syncthreads();
  const float* fin = inst + (size_t)n * CC * HW;
  for (int it = 0; it < 49; ++it) {
    const int flat = it * 256 + t;  // 12544 = 256*49
    const int c = flat / 49, p = flat % 49;
    F[flat] = fin[c * HW + idx[p]];
  }
  __syncthreads();
  if (t < 245) {
    const int p = t % 49, kg = t / 49;  // kg in 0..4
    float acc[32] = {};
    for (int c0 = 0; c0 < 256; c0 += 8) {
      float f[8];
#pragma unroll
      for (int j = 0; j < 8; ++j) f[j] = F[(c0 + j) * 49 + p];
#pragma unroll
      for (int kk = 0; kk < 32; ++kk) {
        const int k = kg + 5 * kk;
        const float* wr = (k < KCLS) ? (w_inst + k * 256) : (w_det + (k - KCLS) * 256);
#pragma unroll
        for (int j = 0; j < 8; ++j) acc[kk] += f[j] * wr[c0 + j];
      }
    }
    const int row = (n * PP + pt * 49 + p) * FCIN + 256;
#pragma unroll
    for (int kk = 0; kk < 32; ++kk) {
      const int k = kg + 5 * kk;
      const float v = acc[kk] + ((k < KCLS) ? b_inst[k] : b_det[k - KCLS]);
      X[row + k] = v;
      Y[row + k] = v;
    }
  }
}

// ---------------- K4b: bilinear-sample sem at roi points -> X head -----------
__global__ __launch_bounds__(256) void fine_sample_k(
    const float* __restrict__ sem, const int* __restrict__ pidx,
    const float* __restrict__ rois, float* __restrict__ X) {
  const int n = blockIdx.x;
  const int t = threadIdx.x;
  const int p = blockIdx.y * 8 + (t >> 5);
  const int c0 = (t & 31) * 8;
  if (p >= PP) return;
  const int idx = pidx[n * PP + p];
  const float rx = ((float)(idx % MW) + 0.5f) / (float)MW;
  const float ry = ((float)(idx / MW) + 0.5f) / (float)MH;
  const float x1 = rois[n * 5 + 1], y1 = rois[n * 5 + 2];
  const float x2 = rois[n * 5 + 3], y2 = rois[n * 5 + 4];
  const float px = (x1 + rx * (x2 - x1)) * 0.25f - 0.5f;
  const float py = (y1 + ry * (y2 - y1)) * 0.25f - 0.5f;
  const float x0f = floorf(px), y0f = floorf(py);
  const int x0 = (int)x0f, y0 = (int)y0f;
  const float wx1 = px - x0f, wy1 = py - y0f;
  float out[8] = {};
#pragma unroll
  for (int cy = 0; cy < 2; ++cy) {
    const int yy = y0 + cy;
    const bool vy = (yy >= 0) && (yy <= SHH - 1);
    const int yc = min(max(yy, 0), SHH - 1);
    const float wy = cy ? wy1 : (1.f - wy1);
#pragma unroll
    for (int cx = 0; cx < 2; ++cx) {
      const int xx = x0 + cx;
      const bool vx = (xx >= 0) && (xx <= SWW - 1);
      const int xc = min(max(xx, 0), SWW - 1);
      const float wgt = (vx && vy) ? wy * (cx ? wx1 : (1.f - wx1)) : 0.f;
      const float* src = sem + ((size_t)yc * SWW + xc) * 256 + c0;
#pragma unroll
      for (int j = 0; j < 8; ++j) out[j] += wgt * src[j];
    }
  }
  float* dst = X + ((size_t)n * PP + p) * FCIN + c0;
#pragma unroll
  for (int j = 0; j < 8; ++j) dst[j] = out[j];
}

// ---------------- K5: MLP layer GEMM (25088 x 256 x 416), relu ---------------
__global__ __launch_bounds__(256) void mlp_gemm_k(
    const float* __restrict__ Xin, const float* __restrict__ w,
    const float* __restrict__ b, float* __restrict__ Xout) {
  __shared__ __align__(16) float A[32 * 68];  // [k][m] padded
  __shared__ __align__(16) float B[32 * 68];  // [k][o] padded
  const int m0 = blockIdx.x * 64, o0 = blockIdx.y * 64;
  const int t = threadIdx.x, tm = t & 15, to = t >> 4;
  float acc[4][4] = {};  // [m][o]
  for (int kc = 0; kc < FCIN; kc += 32) {
#pragma unroll
    for (int it = 0; it < 8; ++it) {
      int flat = it * 256 + t;
      int m = flat >> 5, k = flat & 31;
      A[k * 68 + m] = Xin[(size_t)(m0 + m) * FCIN + kc + k];
      B[k * 68 + m] = w[(size_t)(o0 + m) * FCIN + kc + k];
    }
    __syncthreads();
#pragma unroll
    for (int k = 0; k < 32; ++k) {
      const float4 a4 = *(const float4*)&A[k * 68 + tm * 4];
      const float4 b4 = *(const float4*)&B[k * 68 + to * 4];
      const float av[4] = {a4.x, a4.y, a4.z, a4.w};
      const float bv[4] = {b4.x, b4.y, b4.z, b4.w};
#pragma unroll
      for (int i = 0; i < 4; ++i)
#pragma unroll
        for (int j = 0; j < 4; ++j) acc[i][j] += av[i] * bv[j];
    }
    __syncthreads();
  }
#pragma unroll
  for (int i = 0; i < 4; ++i) {
    float4 r;
    r.x = fmaxf(acc[i][0] + b[o0 + to * 4 + 0], 0.f);
    r.y = fmaxf(acc[i][1] + b[o0 + to * 4 + 1], 0.f);
    r.z = fmaxf(acc[i][2] + b[o0 + to * 4 + 2], 0.f);
    r.w = fmaxf(acc[i][3] + b[o0 + to * 4 + 3], 0.f);
    *(float4*)&Xout[(size_t)(m0 + tm * 4 + i) * FCIN + o0 + to * 4] = r;
  }
}

// ---------------- K6: logits GEMM, scattered into refined (no relu) ----------
__global__ __launch_bounds__(256) void logits_gemm_scatter_k(
    const float* __restrict__ Xin, const float* __restrict__ w,
    const float* __restrict__ b, const int* __restrict__ pidx,
    float* __restrict__ refined) {
  __shared__ __align__(16) float A[32 * 68];
  __shared__ __align__(16) float B[32 * 68];
  const int m0 = blockIdx.x * 64, o0 = blockIdx.y * 64;
  const int t = threadIdx.x, tm = t & 15, to = t >> 4;
  float acc[4][4] = {};
  for (int kc = 0; kc < FCIN; kc += 32) {
#pragma unroll
    for (int it = 0; it < 8; ++it) {
      int flat = it * 256 + t;
      int m = flat >> 5, k = flat & 31;
      A[k * 68 + m] = Xin[(size_t)(m0 + m) * FCIN + kc + k];
      B[k * 68 + m] = w[(size_t)(o0 + m) * FCIN + kc + k];
    }
    __syncthreads();
#pragma unroll
    for (int k = 0; k < 32; ++k) {
      const float4 a4 = *(const float4*)&A[k * 68 + tm * 4];
      const float4 b4 = *(const float4*)&B[k * 68 + to * 4];
      const float av[4] = {a4.x, a4.y, a4.z, a4.w};
      const float bv[4] = {b4.x, b4.y, b4.z, b4.w};
#pragma unroll
      for (int i = 0; i < 4; ++i)
#pragma unroll
        for (int j = 0; j < 4; ++j) acc[i][j] += av[i] * bv[j];
    }
    __syncthreads();
  }
#pragma unroll
  for (int i = 0; i < 4; ++i) {
    const int m = m0 + tm * 4 + i;       // global row = n*196 + p
    const int n = m / PP;
    const int idx = pidx[m];
    float* base = refined + (size_t)n * CC * HW + idx;
#pragma unroll
    for (int j = 0; j < 4; ++j) {
      const int o = o0 + to * 4 + j;
      base[(size_t)o * HW] = acc[i][j] + b[o];
    }
  }
}

// ---------------- K7: grid-stride float4 copy --------------------------------
__global__ void copy4_k(const float4* __restrict__ src, float4* __restrict__ dst, int n4) {
  int i = blockIdx.x * blockDim.x + threadIdx.x;
  const int stride = gridDim.x * blockDim.x;
  for (; i < n4; i += stride) dst[i] = src[i];
}

// ---------------- K8: fuse GEMM: fused = relu(refined . w_fuse^T + b) --------
__global__ __launch_bounds__(256) void fuse_gemm_k(
    const float* __restrict__ refined, const float* __restrict__ w,
    const float* __restrict__ b, float* __restrict__ fused) {
  __shared__ __align__(16) float A[32 * 64];  // [k][s]
  __shared__ __align__(16) float B[32 * 68];  // [k][o]
  const int n = blockIdx.x, s0 = blockIdx.y * 64, o0 = blockIdx.z * 64;
  const int t = threadIdx.x, tm = t & 15, to = t >> 4;
  const float* rn = refined + (size_t)n * CC * HW;
  float acc[4][4] = {};  // [o][m]
  for (int kc = 0; kc < 256; kc += 32) {
#pragma unroll
    for (int it = 0; it < 8; ++it) {
      int flat = it * 256 + t;
      int k = flat >> 6, m = flat & 63;
      const int s = s0 + m;
      A[k * 64 + m] = (s < HW) ? rn[(kc + k) * HW + s] : 0.f;
    }
#pragma unroll
    for (int it = 0; it < 8; ++it) {
      int flat = it * 256 + t;
      int o = flat >> 5, k = flat & 31;
      B[k * 68 + o] = w[(o0 + o) * 256 + kc + k];
    }
    __syncthreads();
#pragma unroll
    for (int k = 0; k < 32; ++k) {
      const float4 a4 = *(const float4*)&A[k * 64 + tm * 4];
      const float4 b4 = *(const float4*)&B[k * 68 + to * 4];
      const float av[4] = {a4.x, a4.y, a4.z, a4.w};
      const float bv[4] = {b4.x, b4.y, b4.z, b4.w};
#pragma unroll
      for (int j = 0; j < 4; ++j)
#pragma unroll
        for (int i = 0; i < 4; ++i) acc[j][i] += av[i] * bv[j];
    }
    __syncthreads();
  }
  const int s = s0 + tm * 4;
  if (s < HW) {
#pragma unroll
    for (int j = 0; j < 4; ++j) {
      const int o = o0 + to * 4 + j;
      float4 r;
      r.x = fmaxf(acc[j][0] + b[o], 0.f);
      r.y = fmaxf(acc[j][1] + b[o], 0.f);
      r.z = fmaxf(acc[j][2] + b[o], 0.f);
      r.w = fmaxf(acc[j][3] + b[o], 0.f);
      *(float4*)&fused[(size_t)n * CC * HW + (size_t)o * HW + s] = r;
    }
  }
}

// ---------------- K9: 2x bilinear upsample (half-pixel, edge-clamped) --------
__global__ __launch_bounds__(256) void upsample_k(const float* __restrict__ fused,
                                                  float* __restrict__ out2) {
  __shared__ float L[HW];
  const int n = blockIdx.x, c = blockIdx.y;
  const float* src = fused + ((size_t)n * CC + c) * HW;
  for (int i = threadIdx.x; i < HW; i += 256) L[i] = src[i];
  __syncthreads();
  float* dst = out2 + ((size_t)n * CC + c) * 3136;
  for (int i = threadIdx.x; i < 3136; i += 256) {
    const int r = i / 56, q = i % 56;
    const float y = fminf(fmaxf(r * 0.5f - 0.25f, 0.f), 27.f);
    const float x = fminf(fmaxf(q * 0.5f - 0.25f, 0.f), 27.f);
    const int y0 = (int)y, x0 = (int)x;
    const float wy1 = y - (float)y0, wx1 = x - (float)x0;
    const int y1 = min(y0 + 1, 27), x1 = min(x0 + 1, 27);
    const float v00 = L[y0 * 28 + x0], v01 = L[y0 * 28 + x1];
    const float v10 = L[y1 * 28 + x0], v11 = L[y1 * 28 + x1];
    const float v = (1.f - wy1) * ((1.f - wx1) * v00 + wx1 * v01) +
                    wy1 * ((1.f - wx1) * v10 + wx1 * v11);
    dst[i] = fmaxf(v, 0.f);
  }
}

// ---------------- host launcher ----------------------------------------------
extern "C" void kernel_launch(void* const* d_in, const int* in_sizes, int n_in,
                              void* d_out, int out_size, void* d_ws, size_t ws_size,
                              hipStream_t stream) {
  (void)in_sizes; (void)n_in; (void)out_size; (void)ws_size;
  const float* inst   = (const float*)d_in[0];
  const float* semf   = (const float*)d_in[1];
  const float* rois   = (const float*)d_in[2];
  const int*   labels = (const int*)d_in[3];
  // d_in[4] = num_points (196), constant
  const float* w_sem  = (const float*)d_in[5];
  const float* b_sem  = (const float*)d_in[6];
  const float* w_inst = (const float*)d_in[7];
  const float* b_inst = (const float*)d_in[8];
  const float* w_det  = (const float*)d_in[9];
  const float* b_det  = (const float*)d_in[10];
  const float* fc_w0  = (const float*)d_in[11];
  const float* fc_b0  = (const float*)d_in[12];
  const float* fc_w1  = (const float*)d_in[13];
  const float* fc_b1  = (const float*)d_in[14];
  const float* fc_w2  = (const float*)d_in[15];
  const float* fc_b2  = (const float*)d_in[16];
  const float* w_log  = (const float*)d_in[17];
  const float* b_log  = (const float*)d_in[18];
  const float* w_fuse = (const float*)d_in[19];
  const float* b_fuse = (const float*)d_in[20];

  float* out0 = (float*)d_out;                  // (N,1,28,28)
  float* out1 = out0 + NN * HW;                 // (N,1,28,28)
  float* out2 = out0 + 2 * NN * HW;             // (N,C,56,56)

  // workspace layout (floats), with lifetime-safe aliasing:
  //   sem     [0,          10,240,000)   dead after fine_sample
  //   X       [10,240,000, 20,676,608)   dead after MLP layer 2
  //   refined [0,          25,690,112)   written by copy4 (after layer 2)
  //   Y       [25,690,112, 36,126,720)   read by logits (disjoint from refined)
  //   fused   [36,126,720, 61,816,832)
  //   pidx    [61,816,832, +25088 ints)
  float* ws      = (float*)d_ws;
  float* sem     = ws;
  float* X       = ws + 10240000;
  float* refined = ws;
  float* Y       = ws + 25690112;
  float* fused   = ws + 36126720;
  int*   pidx    = (int*)(ws + 61816832);

  sem_gemm_k<<<dim3(625, 4), 256, 0, stream>>>(semf, w_sem, b_sem, sem);
  select_maps_k<<<dim3(NN, 4), 256, 0, stream>>>(inst, labels, w_inst, b_inst,
                                                 w_det, b_det, out0, out1);
  topk_k<<<NN, 256, 0, stream>>>(out1, pidx);
  point_kc_k<<<dim3(NN, 4), 256, 0, stream>>>(inst, pidx, w_inst, b_inst,
                                              w_det, b_det, X, Y);
  fine_sample_k<<<dim3(NN, 25), 256, 0, stream>>>(sem, pidx, rois, X);
  mlp_gemm_k<<<dim3(392, 4), 256, 0, stream>>>(X, fc_w0, fc_b0, Y);
  mlp_gemm_k<<<dim3(392, 4), 256, 0, stream>>>(Y, fc_w1, fc_b1, X);
  mlp_gemm_k<<<dim3(392, 4), 256, 0, stream>>>(X, fc_w2, fc_b2, Y);
  copy4_k<<<8192, 256, 0, stream>>>((const float4*)inst, (float4*)refined,
                                    NN * CC * HW / 4);
  logits_gemm_scatter_k<<<dim3(392, 4), 256, 0, stream>>>(Y, w_log, b_log, pidx,
                                                          refined);
  fuse_gemm_k<<<dim3(NN, 13, 4), 256, 0, stream>>>(refined, w_fuse, b_fuse, fused);
  upsample_k<<<dim3(NN, CC), 256, 0, stream>>>(fused, out2);
}

// Round 2
// 1211.874 us; speedup vs baseline: 1.2441x; 1.2441x over previous
//
#include <hip/hip_runtime.h>

// ---------------- problem constants ----------------
#define NN   128
#define CC   256
#define MH   28
#define MW   28
#define HW   784        // 28*28
#define KCLS 80
#define PP   196
#define SHH  200
#define SWW  200
#define SPIX 40000      // 200*200
#define FCIN 416        // C + 2K

typedef __attribute__((ext_vector_type(8))) short short8;
typedef __attribute__((ext_vector_type(4))) float f32x4;

__device__ __forceinline__ unsigned short f2bf(float x) {
  unsigned u = __float_as_uint(x);
  unsigned r = (u + 0x7fffu + ((u >> 16) & 1u)) >> 16;
  return (unsigned short)r;
}

// ---- weight fp32->bf16 convert (concatenated blob) --------------------------
// layout: [w_sem 65536][w_fuse 65536][fc_w0 106496][fc_w1][fc_w2][w_log]
#define OW_SEM  0
#define OW_FUSE 65536
#define OW_FC0  131072
#define OW_FC1  237568
#define OW_FC2  344064
#define OW_LOG  450560
#define OW_TOT  557056
__global__ void wconv_k(const float* __restrict__ wsem, const float* __restrict__ wfuse,
                        const float* __restrict__ w0, const float* __restrict__ w1,
                        const float* __restrict__ w2, const float* __restrict__ wlog,
                        unsigned short* __restrict__ out) {
  for (int i = blockIdx.x * blockDim.x + threadIdx.x; i < OW_TOT;
       i += gridDim.x * blockDim.x) {
    float v;
    if (i < OW_FUSE) v = wsem[i];
    else if (i < OW_FC0) v = wfuse[i - OW_FUSE];
    else if (i < OW_FC1) v = w0[i - OW_FC0];
    else if (i < OW_FC2) v = w1[i - OW_FC1];
    else if (i < OW_LOG) v = w2[i - OW_FC2];
    else v = wlog[i - OW_LOG];
    out[i] = f2bf(v);
  }
}

// ---- transpose+convert: src fp32 [256][P] (c-major) -> dst bf16 [P][256] ----
__global__ __launch_bounds__(256) void transpose_bf16_k(
    const float* __restrict__ src, unsigned short* __restrict__ dst, int P) {
  __shared__ float T[64][69];
  const int t = threadIdx.x;
  src += (size_t)blockIdx.z * 256 * P;
  dst += (size_t)blockIdx.z * P * 256;
  const int p0 = blockIdx.x * 64, c0 = blockIdx.y * 64;
#pragma unroll
  for (int it = 0; it < 16; ++it) {
    int idx = it * 256 + t, c = idx >> 6, p = idx & 63;
    T[c][p] = (p0 + p < P) ? src[(size_t)(c0 + c) * P + p0 + p] : 0.f;
  }
  __syncthreads();
#pragma unroll
  for (int it = 0; it < 16; ++it) {
    int idx = it * 256 + t, p = idx >> 6, c = idx & 63;
    if (p0 + p < P) dst[(size_t)(p0 + p) * 256 + c0 + c] = f2bf(T[c][p]);
  }
}

// ---- generic MFMA bf16 GEMM: D[m][n] = A[m][:] . B[n][:] (both k-innermost) -
// block tile 128x128, 4 waves, wave tile 64x64 (4x4 frags of 16x16x32).
// ASRC: 0 = A fp32 (convert in staging), 1 = A bf16.
// EPI:  0 = mlp   (relu, fp32 out [m][FCIN], bias[n])
//       1 = logits(scatter bf16 rows into refined_t via pidx, bias[n], no relu)
//       2 = sem   (relu, fp32 out [m][256], bias[n])
//       3 = fuse  (relu, fp32 out [m*HW + n] per batch z, bias[m])
template <int ASRC, int EPI>
__global__ __launch_bounds__(256) void gemm_mfma_k(
    const void* __restrict__ Ap, const unsigned short* __restrict__ Bmat,
    const float* __restrict__ bias, float* __restrict__ outf,
    unsigned short* __restrict__ outh, const int* __restrict__ pidx,
    int M, int N, int K, int lda, int ldb) {
  __shared__ __align__(16) unsigned short Abuf[128 * 40];
  __shared__ __align__(16) unsigned short Bbuf[128 * 40];
  const int t = threadIdx.x;
  const int m0 = blockIdx.x * 128, n0 = blockIdx.y * 128;
  if (EPI == 3) {
    Bmat += (size_t)blockIdx.z * HW * 256;
    outf += (size_t)blockIdx.z * CC * HW;
  }
  const float* Af = (const float*)Ap;
  const unsigned short* Ah = (const unsigned short*)Ap;
  const int wave = t >> 6, lane = t & 63, lq = lane >> 4, lr = lane & 15;
  const int msub = (wave & 1) * 64, nsub = (wave >> 1) * 64;
  f32x4 acc[4][4] = {};
  for (int kc = 0; kc < K; kc += 32) {
    // stage A tile (128 rows x 32 k) -> Abuf[r][k], row stride 40
#pragma unroll
    for (int it = 0; it < 4; ++it) {
      const int idx = it * 256 + t, r = idx >> 3, jg = idx & 7;
      const int gm = m0 + r;
      ushort4 h;
      if (ASRC == 0) {
        float4 v = make_float4(0.f, 0.f, 0.f, 0.f);
        if (gm < M) v = *(const float4*)&Af[(size_t)gm * lda + kc + jg * 4];
        h.x = f2bf(v.x); h.y = f2bf(v.y); h.z = f2bf(v.z); h.w = f2bf(v.w);
      } else {
        h = make_ushort4(0, 0, 0, 0);
        if (gm < M) h = *(const ushort4*)&Ah[(size_t)gm * lda + kc + jg * 4];
      }
      *(ushort4*)&Abuf[r * 40 + jg * 4] = h;
    }
    // stage B tile
#pragma unroll
    for (int it = 0; it < 4; ++it) {
      const int idx = it * 256 + t, r = idx >> 3, jg = idx & 7;
      const int gn = n0 + r;
      ushort4 h = make_ushort4(0, 0, 0, 0);
      if (gn < N) h = *(const ushort4*)&Bmat[(size_t)gn * ldb + kc + jg * 4];
      *(ushort4*)&Bbuf[r * 40 + jg * 4] = h;
    }
    __syncthreads();
    short8 af[4], bfr[4];
#pragma unroll
    for (int i = 0; i < 4; ++i)
      af[i] = *(const short8*)&Abuf[(msub + i * 16 + lr) * 40 + lq * 8];
#pragma unroll
    for (int f = 0; f < 4; ++f)
      bfr[f] = *(const short8*)&Bbuf[(nsub + f * 16 + lr) * 40 + lq * 8];
#pragma unroll
    for (int i = 0; i < 4; ++i)
#pragma unroll
      for (int f = 0; f < 4; ++f)
        acc[i][f] = __builtin_amdgcn_mfma_f32_16x16x32_bf16(af[i], bfr[f],
                                                            acc[i][f], 0, 0, 0);
    __syncthreads();
  }
  // epilogue: C/D layout col=lane&15, row=lq*4+reg  [verified m89/m91]
#pragma unroll
  for (int i = 0; i < 4; ++i) {
#pragma unroll
    for (int r = 0; r < 4; ++r) {
      const int gm = m0 + msub + i * 16 + lq * 4 + r;
      if (EPI == 0) {
        if (gm < M) {
#pragma unroll
          for (int f = 0; f < 4; ++f) {
            const int go = n0 + nsub + f * 16 + lr;
            outf[(size_t)gm * FCIN + go] = fmaxf(acc[i][f][r] + bias[go], 0.f);
          }
        }
      } else if (EPI == 1) {
        if (gm < M) {
          const int nimg = gm / PP;
          const int sidx = pidx[gm];
          unsigned short* dst = outh + ((size_t)nimg * HW + sidx) * 256;
#pragma unroll
          for (int f = 0; f < 4; ++f) {
            const int go = n0 + nsub + f * 16 + lr;
            dst[go] = f2bf(acc[i][f][r] + bias[go]);
          }
        }
      } else if (EPI == 2) {
        if (gm < M) {
#pragma unroll
          for (int f = 0; f < 4; ++f) {
            const int go = n0 + nsub + f * 16 + lr;
            outf[(size_t)gm * 256 + go] = fmaxf(acc[i][f][r] + bias[go], 0.f);
          }
        }
      } else {  // EPI == 3: m = out channel, n = spatial
        const float bb = bias[gm];
#pragma unroll
        for (int f = 0; f < 4; ++f) {
          const int gs = n0 + nsub + f * 16 + lr;
          if (gs < N) outf[(size_t)gm * HW + gs] = fmaxf(acc[i][f][r] + bb, 0.f);
        }
      }
    }
  }
}

// ---------------- K2: class-selected inst/det maps (outputs 0 & 1) ----------
// fp64 accumulate so our top-k ranking matches the high-precision reference.
__global__ __launch_bounds__(256) void select_maps_k(
    const float* __restrict__ inst, const int* __restrict__ labels,
    const float* __restrict__ w_inst, const float* __restrict__ b_inst,
    const float* __restrict__ w_det, const float* __restrict__ b_det,
    float* __restrict__ out0, float* __restrict__ out1) {
  const int n = blockIdx.x;
  const int s = blockIdx.y * 196 + threadIdx.x;
  if (threadIdx.x >= 196) return;
  const int lab = labels[n];
  const float* fi = inst + (size_t)n * CC * HW + s;
  const float* wi = w_inst + lab * 256;
  const float* wd = w_det + lab * 256;
  double ai = 0.0, ad = 0.0;
  for (int c = 0; c < 256; ++c) {
    const float v = fi[c * HW];
    ai += (double)v * (double)wi[c];
    ad += (double)v * (double)wd[c];
  }
  out0[n * HW + s] = (float)(ai + (double)b_inst[lab]);
  out1[n * HW + s] = (float)(ad + (double)b_det[lab]);
}

// ---------------- K3: per-n top-196 of 784 via bitonic sort ------------------
__global__ __launch_bounds__(256) void topk_k(const float* __restrict__ det,
                                              int* __restrict__ pidx) {
  __shared__ unsigned long long keys[1024];
  const int n = blockIdx.x;
  for (int i = threadIdx.x; i < 1024; i += 256) {
    unsigned long long kk = 0ull;
    if (i < HW) {
      unsigned u = __float_as_uint(det[n * HW + i]);
      u = (u & 0x80000000u) ? ~u : (u | 0x80000000u);
      kk = ((unsigned long long)u << 32) | (unsigned)(1023 - i);
    }
    keys[i] = kk;
  }
  __syncthreads();
  for (int k = 2; k <= 1024; k <<= 1) {
    for (int j = k >> 1; j > 0; j >>= 1) {
      for (int i = threadIdx.x; i < 1024; i += 256) {
        const int l = i ^ j;
        if (l > i) {
          const bool up = ((i & k) == 0);
          unsigned long long a = keys[i], bb = keys[l];
          if ((a > bb) == up) { keys[i] = bb; keys[l] = a; }
        }
      }
      __syncthreads();
    }
  }
  for (int r = threadIdx.x; r < PP; r += 256)
    pidx[n * PP + r] = 1023 - (int)(keys[828 + r] & 1023ull);
}

// ---------------- K4a: c_inst/c_det at selected points -> X,Y tails ----------
__global__ __launch_bounds__(256) void point_kc_k(
    const float* __restrict__ inst, const int* __restrict__ pidx,
    const float* __restrict__ w_inst, const float* __restrict__ b_inst,
    const float* __restrict__ w_det, const float* __restrict__ b_det,
    float* __restrict__ X, float* __restrict__ Y) {
  __shared__ float F[256 * 49];  // [c][p]
  __shared__ int idx[49];
  const int n = blockIdx.x, pt = blockIdx.y;
  const int t = threadIdx.x;
  if (t < 49) idx[t] = pidx[n * PP + pt * 49 + t];
  __syncthreads();
  const float* fin = inst + (size_t)n * CC * HW;
  for (int it = 0; it < 49; ++it) {
    const int flat = it * 256 + t;
    const int c = flat / 49, p = flat % 49;
    F[flat] = fin[c * HW + idx[p]];
  }
  __syncthreads();
  if (t < 245) {
    const int p = t % 49, kg = t / 49;
    float acc[32] = {};
    for (int c0 = 0; c0 < 256; c0 += 8) {
      float f[8];
#pragma unroll
      for (int j = 0; j < 8; ++j) f[j] = F[(c0 + j) * 49 + p];
#pragma unroll
      for (int kk = 0; kk < 32; ++kk) {
        const int k = kg + 5 * kk;
        const float* wr = (k < KCLS) ? (w_inst + k * 256) : (w_det + (k - KCLS) * 256);
#pragma unroll
        for (int j = 0; j < 8; ++j) acc[kk] += f[j] * wr[c0 + j];
      }
    }
    const int row = (n * PP + pt * 49 + p) * FCIN + 256;
#pragma unroll
    for (int kk = 0; kk < 32; ++kk) {
      const int k = kg + 5 * kk;
      const float v = acc[kk] + ((k < KCLS) ? b_inst[k] : b_det[k - KCLS]);
      X[row + k] = v;
      Y[row + k] = v;
    }
  }
}

// ---------------- K4b: bilinear-sample sem at roi points -> X head -----------
__global__ __launch_bounds__(256) void fine_sample_k(
    const float* __restrict__ sem, const int* __restrict__ pidx,
    const float* __restrict__ rois, float* __restrict__ X) {
  const int n = blockIdx.x;
  const int t = threadIdx.x;
  const int p = blockIdx.y * 8 + (t >> 5);
  const int c0 = (t & 31) * 8;
  if (p >= PP) return;
  const int idx = pidx[n * PP + p];
  const float rx = ((float)(idx % MW) + 0.5f) / (float)MW;
  const float ry = ((float)(idx / MW) + 0.5f) / (float)MH;
  const float x1 = rois[n * 5 + 1], y1 = rois[n * 5 + 2];
  const float x2 = rois[n * 5 + 3], y2 = rois[n * 5 + 4];
  const float px = (x1 + rx * (x2 - x1)) * 0.25f - 0.5f;
  const float py = (y1 + ry * (y2 - y1)) * 0.25f - 0.5f;
  const float x0f = floorf(px), y0f = floorf(py);
  const int x0 = (int)x0f, y0 = (int)y0f;
  const float wx1 = px - x0f, wy1 = py - y0f;
  float out[8] = {};
#pragma unroll
  for (int cy = 0; cy < 2; ++cy) {
    const int yy = y0 + cy;
    const bool vy = (yy >= 0) && (yy <= SHH - 1);
    const int yc = min(max(yy, 0), SHH - 1);
    const float wy = cy ? wy1 : (1.f - wy1);
#pragma unroll
    for (int cx = 0; cx < 2; ++cx) {
      const int xx = x0 + cx;
      const bool vx = (xx >= 0) && (xx <= SWW - 1);
      const int xc = min(max(xx, 0), SWW - 1);
      const float wgt = (vx && vy) ? wy * (cx ? wx1 : (1.f - wx1)) : 0.f;
      const float* src = sem + ((size_t)yc * SWW + xc) * 256 + c0;
#pragma unroll
      for (int j = 0; j < 8; ++j) out[j] += wgt * src[j];
    }
  }
  float* dst = X + ((size_t)n * PP + p) * FCIN + c0;
#pragma unroll
  for (int j = 0; j < 8; ++j) dst[j] = out[j];
}

// ---------------- K9: 2x bilinear upsample (half-pixel, edge-clamped) --------
__global__ __launch_bounds__(256) void upsample_k(const float* __restrict__ fused,
                                                  float* __restrict__ out2) {
  __shared__ float L[HW];
  const int n = blockIdx.x, c = blockIdx.y;
  const float* src = fused + ((size_t)n * CC + c) * HW;
  for (int i = threadIdx.x; i < HW; i += 256) L[i] = src[i];
  __syncthreads();
  float* dst = out2 + ((size_t)n * CC + c) * 3136;
  for (int i = threadIdx.x; i < 3136; i += 256) {
    const int r = i / 56, q = i % 56;
    const float y = fminf(fmaxf(r * 0.5f - 0.25f, 0.f), 27.f);
    const float x = fminf(fmaxf(q * 0.5f - 0.25f, 0.f), 27.f);
    const int y0 = (int)y, x0 = (int)x;
    const float wy1 = y - (float)y0, wx1 = x - (float)x0;
    const int y1 = min(y0 + 1, 27), x1 = min(x0 + 1, 27);
    const float v00 = L[y0 * 28 + x0], v01 = L[y0 * 28 + x1];
    const float v10 = L[y1 * 28 + x0], v11 = L[y1 * 28 + x1];
    const float v = (1.f - wy1) * ((1.f - wx1) * v00 + wx1 * v01) +
                    wy1 * ((1.f - wx1) * v10 + wx1 * v11);
    dst[i] = fmaxf(v, 0.f);
  }
}

// ---------------- host launcher ----------------------------------------------
extern "C" void kernel_launch(void* const* d_in, const int* in_sizes, int n_in,
                              void* d_out, int out_size, void* d_ws, size_t ws_size,
                              hipStream_t stream) {
  (void)in_sizes; (void)n_in; (void)out_size; (void)ws_size;
  const float* inst   = (const float*)d_in[0];
  const float* semf   = (const float*)d_in[1];
  const float* rois   = (const float*)d_in[2];
  const int*   labels = (const int*)d_in[3];
  const float* w_sem  = (const float*)d_in[5];
  const float* b_sem  = (const float*)d_in[6];
  const float* w_inst = (const float*)d_in[7];
  const float* b_inst = (const float*)d_in[8];
  const float* w_det  = (const float*)d_in[9];
  const float* b_det  = (const float*)d_in[10];
  const float* fc_w0  = (const float*)d_in[11];
  const float* fc_b0  = (const float*)d_in[12];
  const float* fc_w1  = (const float*)d_in[13];
  const float* fc_b1  = (const float*)d_in[14];
  const float* fc_w2  = (const float*)d_in[15];
  const float* fc_b2  = (const float*)d_in[16];
  const float* w_log  = (const float*)d_in[17];
  const float* b_log  = (const float*)d_in[18];
  const float* w_fuse = (const float*)d_in[19];
  const float* b_fuse = (const float*)d_in[20];

  float* out0 = (float*)d_out;
  float* out1 = out0 + NN * HW;
  float* out2 = out0 + 2 * NN * HW;

  // workspace layout (float offsets, no aliasing — ~300 MB of >1 GB ws):
  float* ws        = (float*)d_ws;
  float* sem       = ws;                       // 10,240,000 f (40000x256)
  float* X         = ws + 10240000;            // 10,436,608 f (25088x416)
  float* Y         = ws + 20676608;            // 10,436,608 f
  float* fused     = ws + 31113216;            // 25,690,112 f (128x256x784)
  int*   pidx      = (int*)(ws + 56803328);    // 25,088 i
  unsigned short* semf_t    = (unsigned short*)(ws + 56828416);  // 10,240,000 h
  unsigned short* refined_t = (unsigned short*)(ws + 61948416);  // 25,690,112 h
  unsigned short* wbf       = (unsigned short*)(ws + 74793472);  // 557,056 h

  wconv_k<<<512, 256, 0, stream>>>(w_sem, w_fuse, fc_w0, fc_w1, fc_w2, w_log, wbf);
  transpose_bf16_k<<<dim3(625, 4, 1), 256, 0, stream>>>(semf, semf_t, SPIX);
  // sem = relu(semf_t . w_sem^T): M=40000,N=256,K=256
  gemm_mfma_k<1, 2><<<dim3(313, 2, 1), 256, 0, stream>>>(
      semf_t, wbf + OW_SEM, b_sem, sem, nullptr, nullptr, SPIX, 256, 256, 256, 256);
  select_maps_k<<<dim3(NN, 4), 256, 0, stream>>>(inst, labels, w_inst, b_inst,
                                                 w_det, b_det, out0, out1);
  topk_k<<<NN, 256, 0, stream>>>(out1, pidx);
  point_kc_k<<<dim3(NN, 4), 256, 0, stream>>>(inst, pidx, w_inst, b_inst,
                                              w_det, b_det, X, Y);
  fine_sample_k<<<dim3(NN, 25), 256, 0, stream>>>(sem, pidx, rois, X);
  // MLP: M=25088,N=256,K=416
  gemm_mfma_k<0, 0><<<dim3(196, 2, 1), 256, 0, stream>>>(
      X, wbf + OW_FC0, fc_b0, Y, nullptr, nullptr, NN * PP, 256, FCIN, FCIN, FCIN);
  gemm_mfma_k<0, 0><<<dim3(196, 2, 1), 256, 0, stream>>>(
      Y, wbf + OW_FC1, fc_b1, X, nullptr, nullptr, NN * PP, 256, FCIN, FCIN, FCIN);
  gemm_mfma_k<0, 0><<<dim3(196, 2, 1), 256, 0, stream>>>(
      X, wbf + OW_FC2, fc_b2, Y, nullptr, nullptr, NN * PP, 256, FCIN, FCIN, FCIN);
  // refined_t = bf16 transpose of inst, then logits scattered into it
  transpose_bf16_k<<<dim3(13, 4, NN), 256, 0, stream>>>(inst, refined_t, HW);
  gemm_mfma_k<0, 1><<<dim3(196, 2, 1), 256, 0, stream>>>(
      Y, wbf + OW_LOG, b_log, nullptr, refined_t, pidx, NN * PP, 256, FCIN, FCIN, FCIN);
  // fuse: per n, D[o][s] = w_fuse[o][:] . refined_t[n][s][:]
  gemm_mfma_k<1, 3><<<dim3(2, 7, NN), 256, 0, stream>>>(
      wbf + OW_FUSE, refined_t, b_fuse, fused, nullptr, nullptr, 256, HW, 256, 256, 256);
  upsample_k<<<dim3(NN, CC), 256, 0, stream>>>(fused, out2);
}